// Round 4
// baseline (770.547 us; speedup 1.0000x reference)
//
#include <hip/hip_runtime.h>
#include <hip/hip_bf16.h>

// x [B=64, C=256, H=32, W=32] f32; embedding [K=4096, D=256] f32
// N = 65536 rows. Outputs: out[B,C,H,W] f32 (16777216), loss, perplexity.

#define K_CODES 4096

typedef __attribute__((ext_vector_type(8))) short bf16x8;
typedef __attribute__((ext_vector_type(4))) float f32x4;
typedef __attribute__((ext_vector_type(8))) unsigned short u16x8;

__device__ __forceinline__ void gload_lds16(const void* g, void* l) {
    __builtin_amdgcn_global_load_lds((const __attribute__((address_space(1))) unsigned int*)g,
                                     (__attribute__((address_space(3))) unsigned int*)l,
                                     16, 0, 0);
}

__device__ __forceinline__ unsigned short f2bf(float v) {
    __hip_bfloat16 h = __float2bfloat16(v);
    return *(unsigned short*)&h;
}

// ---------------- emb f32 -> bf16, plus SeN[k] = -0.5 * sum_d e[k][d]^2 ----------------
__global__ __launch_bounds__(64) void vq_prep_emb(const float* __restrict__ emb,
                                                  unsigned short* __restrict__ embB,
                                                  float* __restrict__ SeN) {
    const int k = blockIdx.x, t = threadIdx.x;
    const float* e = emb + ((size_t)k << 8) + t * 4;
    float4 v = *(const float4*)e;
    ushort4 o;
    o.x = f2bf(v.x); o.y = f2bf(v.y); o.z = f2bf(v.z); o.w = f2bf(v.w);
    *(ushort4*)(embB + ((size_t)k << 8) + t * 4) = o;
    float s = v.x * v.x + v.y * v.y + v.z * v.z + v.w * v.w;
#pragma unroll
    for (int m = 1; m < 64; m <<= 1) s += __shfl_xor(s, m, 64);
    if (t == 0) SeN[k] = -0.5f * s;
}

// ---------------- x [b][c][hw] f32 -> xT [b*1024+hw][c] bf16 ----------------
__global__ __launch_bounds__(256) void vq_transpose(const float* __restrict__ x,
                                                    unsigned short* __restrict__ xT) {
    __shared__ float tile[64][65];
    const int bid = blockIdx.x;
    const int ht = bid & 15, ct = (bid >> 4) & 3, b = bid >> 6;
    const int hw0 = ht * 64, c0 = ct * 64;
    const int t = threadIdx.x;
    {
        const int hwl = t & 63, cl = t >> 6;  // cl 0..3
        const float* xp = x + ((size_t)b << 18) + ((size_t)c0 << 10) + hw0 + hwl;
#pragma unroll
        for (int i = 0; i < 16; ++i)
            tile[cl + i * 4][hwl] = xp[(size_t)(cl + i * 4) << 10];
    }
    __syncthreads();
    {
        const int hwl = t >> 2, cs = (t & 3) * 16;
        unsigned short* op = xT + ((size_t)(b * 1024 + hw0 + hwl) << 8) + c0 + cs;
        u16x8 p0, p1;
#pragma unroll
        for (int j = 0; j < 8; ++j) p0[j] = f2bf(tile[cs + j][hwl]);
#pragma unroll
        for (int j = 0; j < 8; ++j) p1[j] = f2bf(tile[cs + 8 + j][hwl]);
        *(u16x8*)op = p0;
        *(u16x8*)(op + 8) = p1;
    }
}

// ---------------- MFMA argmin, barrier-free K-loop ----------------
// 512 blocks x 256 thr (4 waves). Rows/block = 128 shared via LDS xs (64KB, swizzled).
// Wave w owns codes [w*1024, (w+1)*1024) in chunks of 64 (4 cfrags of 16).
// B-fragments load DIRECTLY from global embB (L2/L1-resident; no LDS, no barriers).
// acc frag (rf,cf): C-init = -Se/2, so final acc = dot - Se/2; argmin score == argmax acc.
// Per-row combine across waves/blocks: packed key (ordered-uint | (4095-code)) + atomicMax.
__global__ __launch_bounds__(256, 2) void vq_argmin_mfma(
    const unsigned short* __restrict__ xT,
    const unsigned short* __restrict__ embB,
    const float* __restrict__ SeN,
    unsigned int* __restrict__ keys) {
    extern __shared__ char xsb[];  // 65536 B: xs[128 rows][512 B], XOR-swizzled

    const int t = threadIdx.x;
    const int w = t >> 6;
    const int l = t & 63;
    const int h = l >> 4;   // k-group 0..3 (k = h*8 + j)
    const int r = l & 15;   // row-within-frag (A/C) / code-within-frag (B/C)
    const int n0 = blockIdx.x * 128;

    // stage xs: LDS[row][col] = xT[n0+row][(col ^ ((row&15)<<4))/2], linear dest
#pragma unroll
    for (int i = 0; i < 16; ++i) {
        const int obase = (w * 16 + i) * 1024;  // wave-uniform
        const int o = obase + l * 16;
        const int row = o >> 9;
        const int scol = (o & 511) ^ ((row & 15) << 4);
        gload_lds16(xT + ((size_t)(n0 + row) << 8) + (scol >> 1), xsb + obase);
    }
    __syncthreads();  // drains vmcnt; the ONLY barrier

    unsigned int best[32];
#pragma unroll
    for (int s = 0; s < 32; ++s) best[s] = 0u;

    const int swz = r << 4;

    for (int ch = 0; ch < 16; ++ch) {
        const int cb = w * 1024 + ch * 64;
        float nh[4];
        unsigned int lowb[4];
#pragma unroll
        for (int cf = 0; cf < 4; ++cf) {
            nh[cf] = SeN[cb + cf * 16 + r];
            lowb[cf] = 4095u - (unsigned int)(cb + cf * 16 + r);
        }
        f32x4 acc[8][4];
#pragma unroll
        for (int rf = 0; rf < 8; ++rf)
#pragma unroll
            for (int cf = 0; cf < 4; ++cf)
                acc[rf][cf] = (f32x4){nh[cf], nh[cf], nh[cf], nh[cf]};

        const unsigned short* pB0 = embB + ((size_t)(cb + r) << 8) + h * 8;

#pragma unroll
        for (int dkk = 0; dkk < 8; ++dkk) {
            const int dk = dkk * 32;
            bf16x8 bv[4];
#pragma unroll
            for (int cf = 0; cf < 4; ++cf)
                bv[cf] = *(const bf16x8*)(pB0 + cf * 4096 + dk);
            bf16x8 af[8];
#pragma unroll
            for (int rf = 0; rf < 8; ++rf) {
                const int row = rf * 16 + r;
                af[rf] = *(const bf16x8*)(xsb + row * 512 + (((dk + h * 8) * 2) ^ swz));
            }
#pragma unroll
            for (int cf = 0; cf < 4; ++cf)
#pragma unroll
                for (int rf = 0; rf < 8; ++rf)
                    acc[rf][cf] = __builtin_amdgcn_mfma_f32_16x16x32_bf16(
                        af[rf], bv[cf], acc[rf][cf], 0, 0, 0);
        }

        // fold chunk into running packed-key max (argmax acc == argmin score)
#pragma unroll
        for (int rf = 0; rf < 8; ++rf)
#pragma unroll
            for (int cf = 0; cf < 4; ++cf)
#pragma unroll
                for (int reg = 0; reg < 4; ++reg) {
                    const unsigned int u = __float_as_uint(acc[rf][cf][reg]);
                    unsigned int key = u ^ (0x80000000u | (unsigned int)((int)u >> 31));
                    key = (key & 0xFFFFF000u) | lowb[cf];
                    const int s = rf * 4 + reg;
                    best[s] = best[s] > key ? best[s] : key;
                }
    }

    // reduce over the 16 code-lanes (same h), then per-row global atomicMax
#pragma unroll
    for (int s = 0; s < 32; ++s) {
        unsigned int k = best[s];
#pragma unroll
        for (int m = 1; m <= 8; m <<= 1) {
            const unsigned int o = __shfl_xor(k, m, 64);
            k = k > o ? k : o;
        }
        if (r == 0)
            atomicMax(&keys[n0 + (s >> 2) * 16 + h * 4 + (s & 3)], k);
    }
}

// ---------------- fused quantized output + MSE + histogram ----------------
// grid = B*C blocks (16384); block 256 threads, each thread 4 hw via float4.
__global__ __launch_bounds__(256) void vq_out(const float* __restrict__ x,
                                              const float* __restrict__ emb,
                                              const unsigned int* __restrict__ keys,
                                              float* __restrict__ out,
                                              double* __restrict__ loss_acc,
                                              unsigned int* __restrict__ counts) {
    __shared__ double sd[256];
    const int t = threadIdx.x;
    const int bc = blockIdx.x;  // b*256 + c
    const int b = bc >> 8, c = bc & 255;
    const size_t base = (size_t)bc << 10;
    const int hw = t * 4;
    float4 xv = *(const float4*)(x + base + hw);
    uint4 kv = *(const uint4*)(keys + (b << 10) + hw);
    const int c0 = 4095 - (int)(kv.x & 0xFFFu);
    const int c1 = 4095 - (int)(kv.y & 0xFFFu);
    const int c2 = 4095 - (int)(kv.z & 0xFFFu);
    const int c3 = 4095 - (int)(kv.w & 0xFFFu);
    if (c == 0) {  // one block per b does the code histogram (once per row)
        atomicAdd(&counts[c0], 1u);
        atomicAdd(&counts[c1], 1u);
        atomicAdd(&counts[c2], 1u);
        atomicAdd(&counts[c3], 1u);
    }
    const float q0 = emb[((size_t)c0 << 8) + c];
    const float q1 = emb[((size_t)c1 << 8) + c];
    const float q2 = emb[((size_t)c2 << 8) + c];
    const float q3 = emb[((size_t)c3 << 8) + c];
    const float d0 = q0 - xv.x, d1 = q1 - xv.y, d2 = q2 - xv.z, d3 = q3 - xv.w;
    float4 o;
    o.x = xv.x + d0;
    o.y = xv.y + d1;
    o.z = xv.z + d2;
    o.w = xv.w + d3;
    *(float4*)(out + base + hw) = o;
    sd[t] = (double)d0 * d0 + (double)d1 * d1 + (double)d2 * d2 + (double)d3 * d3;
    __syncthreads();
    for (int off = 128; off > 0; off >>= 1) {
        if (t < off) sd[t] += sd[t + off];
        __syncthreads();
    }
    if (t == 0) atomicAdd(loss_acc, sd[0]);
}

// ---------------- finalize loss + perplexity ----------------
__global__ __launch_bounds__(256) void vq_final(const unsigned int* __restrict__ counts,
                                                const double* __restrict__ loss_acc,
                                                float* __restrict__ out_scalars) {
    __shared__ double sd[256];
    const int t = threadIdx.x;
    double s = 0.0;
    for (int j = t; j < K_CODES; j += 256) {
        const double p = (double)counts[j] * (1.0 / 65536.0);
        s += p * log(p + 1e-10);
    }
    sd[t] = s;
    __syncthreads();
    for (int off = 128; off > 0; off >>= 1) {
        if (t < off) sd[t] += sd[t + off];
        __syncthreads();
    }
    if (t == 0) {
        const double mse = loss_acc[0] / 16777216.0;
        out_scalars[0] = (float)(1.25 * mse);
        out_scalars[1] = (float)exp(-sd[0]);
    }
}

extern "C" void kernel_launch(void* const* d_in, const int* in_sizes, int n_in,
                              void* d_out, int out_size, void* d_ws, size_t ws_size,
                              hipStream_t stream) {
    const float* x = (const float*)d_in[0];    // 16777216 f32
    const float* emb = (const float*)d_in[1];  // 1048576 f32
    float* out = (float*)d_out;

    char* ws = (char*)d_ws;
    double* loss_acc = (double*)ws;                         // @0, 8 B
    unsigned int* counts = (unsigned int*)(ws + 1024);      // 16 KB -> ends 17408
    unsigned int* keys = (unsigned int*)(ws + 17408);       // 256 KB -> ends 279552
    float* SeN = (float*)(ws + 279552);                     // 16 KB -> ends 295936
    unsigned short* embB = (unsigned short*)(ws + 295936);  // 2 MB -> ends 2393088
    unsigned short* xT = (unsigned short*)(ws + 2393088);   // 32 MB bf16

    hipMemsetAsync(ws, 0, 279552, stream);  // loss_acc + counts + keys
    vq_prep_emb<<<K_CODES, 64, 0, stream>>>(emb, embB, SeN);
    vq_transpose<<<4096, 256, 0, stream>>>(x, xT);
    vq_argmin_mfma<<<512, 256, 65536, stream>>>(xT, embB, SeN, keys);
    vq_out<<<64 * 256, 256, 0, stream>>>(x, emb, keys, out, loss_acc, counts);
    vq_final<<<1, 256, 0, stream>>>(counts, loss_acc, out + (out_size - 2));
}

// Round 6
// 575.198 us; speedup vs baseline: 1.3396x; 1.3396x over previous
//
#include <hip/hip_runtime.h>
#include <hip/hip_bf16.h>

// x [B=64, C=256, H=32, W=32] f32; embedding [K=4096, D=256] f32
// N = 65536 rows. Outputs: out[B,C,H,W] f32 (16777216), loss, perplexity.

#define K_CODES 4096

typedef __attribute__((ext_vector_type(8))) short bf16x8;
typedef __attribute__((ext_vector_type(4))) float f32x4;

__device__ __forceinline__ unsigned short f2bf(float v) {
    __hip_bfloat16 h = __float2bfloat16(v);
    return *(unsigned short*)&h;
}

// ---------------- emb f32 -> bf16, plus SeN[k] = -0.5 * sum_d e[k][d]^2 ----------------
__global__ __launch_bounds__(64) void vq_prep_emb(const float* __restrict__ emb,
                                                  unsigned short* __restrict__ embB,
                                                  float* __restrict__ SeN) {
    const int k = blockIdx.x, t = threadIdx.x;
    const float* e = emb + ((size_t)k << 8) + t * 4;
    float4 v = *(const float4*)e;
    ushort4 o;
    o.x = f2bf(v.x); o.y = f2bf(v.y); o.z = f2bf(v.z); o.w = f2bf(v.w);
    *(ushort4*)(embB + ((size_t)k << 8) + t * 4) = o;
    float s = v.x * v.x + v.y * v.y + v.z * v.z + v.w * v.w;
#pragma unroll
    for (int m = 1; m < 64; m <<= 1) s += __shfl_xor(s, m, 64);
    if (t == 0) SeN[k] = -0.5f * s;
}

// ---------------- MFMA argmin, fused x-transpose, barrier-light ----------------
// 1024 blocks x 256 thr (4 waves). Block owns 64 rows (staged bf16+swizzled in LDS).
// Wave w scans codes [w*1024,(w+1)*1024) in 16 chunks of 64 (4 cfrags), rf=4 row frags.
// B-fragments load directly from global embB (L1/L2-resident). acc C-init = -Se/2 so
// argmin dist == argmax acc. Packed key (ordered-uint | (4095-code)); cross-wave
// combine in LDS; block writes idx + histogram directly.
__global__ __launch_bounds__(256, 2) void vq_argmin_mfma(
    const float* __restrict__ x,
    const unsigned short* __restrict__ embB,
    const float* __restrict__ SeN,
    int* __restrict__ idx_out,
    unsigned int* __restrict__ counts) {
    __shared__ __align__(16) char xsb[32768];  // xs[64 rows][512 B], XOR-swizzled

    const int t = threadIdx.x;
    const int w = t >> 6;
    const int l = t & 63;
    const int h = l >> 4;   // k-group 0..3
    const int r = l & 15;   // row-within-frag (A) / code-within-frag (B)
    const int n0 = blockIdx.x * 64;
    const int b = n0 >> 10;
    const int hw0 = n0 & 1023;

    // ---- stage x[b][:, hw0..hw0+63] -> bf16, transposed, swizzled ----
    {
        const int cpair = t & 127;  // handles channels c0, c0+1
        const int half = t >> 7;    // hw half (32 rows)
        const int c0 = cpair * 2;
        const int hwb = half * 32;
        const float* p0 = x + ((size_t)b << 18) + ((size_t)c0 << 10) + hw0 + hwb;
        const float* p1 = p0 + 1024;
#pragma unroll
        for (int q = 0; q < 8; ++q) {
            float4 a0 = *(const float4*)(p0 + q * 4);
            float4 a1 = *(const float4*)(p1 + q * 4);
#pragma unroll
            for (int e = 0; e < 4; ++e) {
                const int j = hwb + q * 4 + e;  // row (hw offset)
                const unsigned int pk =
                    (unsigned int)f2bf((&a0.x)[e]) | ((unsigned int)f2bf((&a1.x)[e]) << 16);
                *(unsigned int*)(xsb + j * 512 + ((c0 * 2) ^ ((j & 15) << 4))) = pk;
            }
        }
    }
    __syncthreads();

    unsigned int best[16];
#pragma unroll
    for (int s = 0; s < 16; ++s) best[s] = 0u;

    const int swzr = r << 4;

    for (int ch = 0; ch < 16; ++ch) {
        const int cb = w * 1024 + ch * 64;
        float nh[4];
        unsigned int lowb[4];
#pragma unroll
        for (int cf = 0; cf < 4; ++cf) {
            nh[cf] = SeN[cb + cf * 16 + r];
            lowb[cf] = 4095u - (unsigned int)(cb + cf * 16 + r);
        }
        f32x4 acc[4][4];
#pragma unroll
        for (int rf = 0; rf < 4; ++rf)
#pragma unroll
            for (int cf = 0; cf < 4; ++cf)
                acc[rf][cf] = (f32x4){nh[cf], nh[cf], nh[cf], nh[cf]};

        const unsigned short* pB0 = embB + ((size_t)(cb + r) << 8) + h * 8;

#pragma unroll
        for (int dkk = 0; dkk < 8; ++dkk) {
            const int dk = dkk * 32;
            bf16x8 bv[4];
#pragma unroll
            for (int cf = 0; cf < 4; ++cf)
                bv[cf] = *(const bf16x8*)(pB0 + cf * 4096 + dk);
            bf16x8 af[4];
#pragma unroll
            for (int rf = 0; rf < 4; ++rf)
                af[rf] = *(const bf16x8*)(xsb + (rf * 16 + r) * 512 +
                                          (((dk + h * 8) * 2) ^ swzr));
#pragma unroll
            for (int cf = 0; cf < 4; ++cf)
#pragma unroll
                for (int rf = 0; rf < 4; ++rf)
                    acc[rf][cf] = __builtin_amdgcn_mfma_f32_16x16x32_bf16(
                        af[rf], bv[cf], acc[rf][cf], 0, 0, 0);
        }

        // fold chunk into running packed-key max (argmax acc == argmin dist)
#pragma unroll
        for (int rf = 0; rf < 4; ++rf)
#pragma unroll
            for (int cf = 0; cf < 4; ++cf)
#pragma unroll
                for (int reg = 0; reg < 4; ++reg) {
                    const unsigned int u = __float_as_uint(acc[rf][cf][reg]);
                    unsigned int key = u ^ (0x80000000u | (unsigned int)((int)u >> 31));
                    key = (key & 0xFFFFF000u) | lowb[cf];
                    const int s = rf * 4 + reg;
                    best[s] = best[s] > key ? best[s] : key;
                }
    }

    // reduce over the 16 code-lanes (same h)
#pragma unroll
    for (int s = 0; s < 16; ++s) {
        unsigned int k = best[s];
#pragma unroll
        for (int m = 1; m <= 8; m <<= 1) {
            const unsigned int o = __shfl_xor(k, m, 64);
            k = k > o ? k : o;
        }
        best[s] = k;  // valid at r == 0
    }

    // cross-wave combine in LDS (xsb no longer needed after this barrier)
    __syncthreads();
    unsigned int* keybuf = (unsigned int*)xsb;  // [4][64]
    if (r == 0) {
#pragma unroll
        for (int s = 0; s < 16; ++s)
            keybuf[w * 64 + (s >> 2) * 16 + h * 4 + (s & 3)] = best[s];
    }
    __syncthreads();
    if (t < 64) {
        unsigned int k0 = keybuf[t], k1 = keybuf[64 + t];
        unsigned int k2 = keybuf[128 + t], k3 = keybuf[192 + t];
        k0 = k0 > k1 ? k0 : k1;
        k2 = k2 > k3 ? k2 : k3;
        k0 = k0 > k2 ? k0 : k2;
        const int code = 4095 - (int)(k0 & 0xFFFu);
        idx_out[n0 + t] = code;
        atomicAdd(&counts[code], 1u);
    }
}

// ---------------- fused quantized output + MSE accumulation ----------------
__global__ __launch_bounds__(256) void vq_out(const float* __restrict__ x,
                                              const float* __restrict__ emb,
                                              const int* __restrict__ idx,
                                              float* __restrict__ out,
                                              double* __restrict__ loss_acc) {
    __shared__ double sd[256];
    const int t = threadIdx.x;
    const int bc = blockIdx.x;  // b*256 + c
    const int b = bc >> 8, c = bc & 255;
    const size_t base = (size_t)bc << 10;
    const int hw = t * 4;
    float4 xv = *(const float4*)(x + base + hw);
    int4 iv = *(const int4*)(idx + (b << 10) + hw);
    const float q0 = emb[((size_t)iv.x << 8) + c];
    const float q1 = emb[((size_t)iv.y << 8) + c];
    const float q2 = emb[((size_t)iv.z << 8) + c];
    const float q3 = emb[((size_t)iv.w << 8) + c];
    const float d0 = q0 - xv.x, d1 = q1 - xv.y, d2 = q2 - xv.z, d3 = q3 - xv.w;
    float4 o;
    o.x = xv.x + d0;
    o.y = xv.y + d1;
    o.z = xv.z + d2;
    o.w = xv.w + d3;
    *(float4*)(out + base + hw) = o;
    sd[t] = (double)d0 * d0 + (double)d1 * d1 + (double)d2 * d2 + (double)d3 * d3;
    __syncthreads();
    for (int off = 128; off > 0; off >>= 1) {
        if (t < off) sd[t] += sd[t + off];
        __syncthreads();
    }
    if (t == 0) atomicAdd(loss_acc, sd[0]);
}

// ---------------- finalize loss + perplexity ----------------
__global__ __launch_bounds__(256) void vq_final(const unsigned int* __restrict__ counts,
                                                const double* __restrict__ loss_acc,
                                                float* __restrict__ out_scalars) {
    __shared__ double sd[256];
    const int t = threadIdx.x;
    double s = 0.0;
    for (int j = t; j < K_CODES; j += 256) {
        const double p = (double)counts[j] * (1.0 / 65536.0);
        s += p * log(p + 1e-10);
    }
    sd[t] = s;
    __syncthreads();
    for (int off = 128; off > 0; off >>= 1) {
        if (t < off) sd[t] += sd[t + off];
        __syncthreads();
    }
    if (t == 0) {
        const double mse = loss_acc[0] / 16777216.0;
        out_scalars[0] = (float)(1.25 * mse);
        out_scalars[1] = (float)exp(-sd[0]);
    }
}

extern "C" void kernel_launch(void* const* d_in, const int* in_sizes, int n_in,
                              void* d_out, int out_size, void* d_ws, size_t ws_size,
                              hipStream_t stream) {
    const float* x = (const float*)d_in[0];    // 16777216 f32
    const float* emb = (const float*)d_in[1];  // 1048576 f32
    float* out = (float*)d_out;

    char* ws = (char*)d_ws;
    double* loss_acc = (double*)ws;                         // @0, 8 B
    unsigned int* counts = (unsigned int*)(ws + 1024);      // 16 KB -> ends 17408
    float* SeN = (float*)(ws + 20480);                      // 16 KB -> ends 36864
    int* idx = (int*)(ws + 40960);                          // 256 KB -> ends 303104
    unsigned short* embB = (unsigned short*)(ws + 303104);  // 2 MB bf16

    hipMemsetAsync(ws, 0, 20480, stream);  // loss_acc + counts
    vq_prep_emb<<<K_CODES, 64, 0, stream>>>(emb, embB, SeN);
    vq_argmin_mfma<<<1024, 256, 0, stream>>>(x, embB, SeN, idx, counts);
    vq_out<<<64 * 256, 256, 0, stream>>>(x, emb, idx, out, loss_acc);
    vq_final<<<1, 256, 0, stream>>>(counts, loss_acc, out + (out_size - 2));
}